// Round 3
// baseline (296.462 us; speedup 1.0000x reference)
//
#include <hip/hip_runtime.h>

#define T_SEQ 2048
#define DIM   768
#define NH    12
#define HD    64

typedef __attribute__((ext_vector_type(8))) short short8;
typedef __attribute__((ext_vector_type(4))) float floatx4;
typedef __attribute__((ext_vector_type(4))) unsigned short ushort4v;

#define MFMA16(a,b,c) __builtin_amdgcn_mfma_f32_16x16x32_bf16((a),(b),(c),0,0,0)

static __device__ __forceinline__ unsigned short f2bf(float f){
  union { float f; unsigned u; } v; v.f = f;
  unsigned r = v.u + 0x7fffu + ((v.u >> 16) & 1u);
  return (unsigned short)(r >> 16);
}

// ---------------- fp32 -> bf16 conversion of x, Wq|Wk|Wv, Wp ----------------
__global__ void convert_kernel(const float* __restrict__ x,
                               const float* __restrict__ wq,
                               const float* __restrict__ wk,
                               const float* __restrict__ wv,
                               const float* __restrict__ wp,
                               unsigned short* __restrict__ xb,
                               unsigned short* __restrict__ wqkvb,
                               unsigned short* __restrict__ wpb){
  const int stride = gridDim.x * blockDim.x;
  const int i0 = blockIdx.x * blockDim.x + threadIdx.x;
  const int XN = T_SEQ * DIM;
  const int WN = DIM * DIM;
  for (int i = i0; i < XN; i += stride) xb[i] = f2bf(x[i]);
  for (int i = i0; i < WN; i += stride) {
    wqkvb[i]        = f2bf(wq[i]);
    wqkvb[WN + i]   = f2bf(wk[i]);
    wqkvb[2*WN + i] = f2bf(wv[i]);
    wpb[i]          = f2bf(wp[i]);
  }
}

// ---------------- QKV projection + lerp + rmsnorm + rope --------------------
// grid (32 row-blocks, 36 col-blocks): cb/12 = {q,k,v}, cb%12 = head
__global__ __launch_bounds__(256) void qkv_kernel(
    const unsigned short* __restrict__ xb,
    const unsigned short* __restrict__ wqkvb,
    const float* __restrict__ vi,
    const float* __restrict__ lambp,
    unsigned short* __restrict__ qb,   // [NH][T][HD]
    unsigned short* __restrict__ kb,   // [NH][T][HD]
    unsigned short* __restrict__ vT){  // [NH][HD][T]
  const int w  = threadIdx.x >> 6;
  const int l  = threadIdx.x & 63;
  const int lr = l & 15, lq = l >> 4;
  const int rb = blockIdx.x, cb = blockIdx.y;
  const int mat = cb / NH, head = cb % NH;
  const int row0 = rb*64 + w*16;

  floatx4 acc[4];
  #pragma unroll
  for (int nt=0; nt<4; nt++) acc[nt] = (floatx4){0.f,0.f,0.f,0.f};

  const unsigned short* arow = xb + (size_t)(row0 + lr)*DIM + lq*8;
  const unsigned short* b0   = wqkvb + (size_t)mat*DIM*DIM
                             + (size_t)(head*HD + lr)*DIM + lq*8;
  for (int k0 = 0; k0 < DIM; k0 += 32){
    short8 a = *(const short8*)(arow + k0);
    #pragma unroll
    for (int nt = 0; nt < 4; nt++){
      short8 b = *(const short8*)(b0 + (size_t)nt*16*DIM + k0);
      acc[nt] = MFMA16(a, b, acc[nt]);
    }
  }

  if (mat == 2){
    // v = (1-lamb)*v + lamb*vi, store transposed vT[head][d][t]
    const float lamb = *lambp;
    const int tb = row0 + lq*4;
    #pragma unroll
    for (int nt=0; nt<4; nt++){
      const int d = nt*16 + lr;
      ushort4v pk;
      #pragma unroll
      for (int r=0; r<4; r++){
        float vv = (1.0f - lamb)*acc[nt][r]
                 + lamb * vi[(size_t)(tb + r)*DIM + head*HD + d];
        pk[r] = f2bf(vv);
      }
      *(ushort4v*)(vT + (size_t)(head*HD + d)*T_SEQ + tb) = pk;
    }
  } else {
    // rmsnorm over the 64-wide head dim (row spread across 16 lanes x 4 tiles)
    float ss[4];
    #pragma unroll
    for (int r=0; r<4; r++)
      ss[r] = acc[0][r]*acc[0][r] + acc[1][r]*acc[1][r]
            + acc[2][r]*acc[2][r] + acc[3][r]*acc[3][r];
    #pragma unroll
    for (int mm=1; mm<16; mm<<=1){
      #pragma unroll
      for (int r=0; r<4; r++) ss[r] += __shfl_xor(ss[r], mm);
    }
    float scl[4];
    #pragma unroll
    for (int r=0; r<4; r++)
      scl[r] = rsqrtf(ss[r]*(1.0f/64.0f) + 1.1920929e-7f);

    unsigned short* dst = (mat==0 ? qb : kb) + (size_t)head*T_SEQ*HD;
    #pragma unroll
    for (int nt=0; nt<2; nt++){
      const int i = nt*16 + lr;                 // rope pair index, 0..31
      const float inv = __expf(-(float)i * (9.210340371976184f/32.0f));
      #pragma unroll
      for (int r=0; r<4; r++){
        const int t = row0 + lq*4 + r;
        const float f = (float)t * inv;
        const float c = cosf(f), s = sinf(f);
        const float x1 = acc[nt][r]*scl[r], x2 = acc[nt+2][r]*scl[r];
        dst[(size_t)t*HD + i]      = f2bf(x1*c + x2*s);
        dst[(size_t)t*HD + i + 32] = f2bf(x2*c - x1*s);
      }
    }
  }
}

// ---------------- causal flash attention (MFMA) ------------------------------
// grid (32 q-blocks, 12 heads); block = 4 waves; each wave owns 16 q-rows.
__global__ __launch_bounds__(256) void attn_kernel(
    const unsigned short* __restrict__ qb,
    const unsigned short* __restrict__ kb,
    const unsigned short* __restrict__ vT,
    unsigned short* __restrict__ yb){   // [T][DIM] token-major
  __shared__ unsigned short plds[2][4][16*40];  // double-buffered P, pad 40
  const int w  = threadIdx.x >> 6;
  const int l  = threadIdx.x & 63;
  const int lr = l & 15, lq = l >> 4;
  const int head = blockIdx.y;
  const int q0 = blockIdx.x*64 + w*16;

  const unsigned short* Q = qb + (size_t)head*T_SEQ*HD;
  const unsigned short* K = kb + (size_t)head*T_SEQ*HD;
  const unsigned short* V = vT + (size_t)head*HD*T_SEQ;

  const short8 qf0 = *(const short8*)(Q + (size_t)(q0+lr)*HD + lq*8);
  const short8 qf1 = *(const short8*)(Q + (size_t)(q0+lr)*HD + 32 + lq*8);

  floatx4 O[4];
  #pragma unroll
  for (int nt=0; nt<4; nt++) O[nt] = (floatx4){0.f,0.f,0.f,0.f};
  float m[4]    = {-1e30f,-1e30f,-1e30f,-1e30f};
  float lsum[4] = {0.f,0.f,0.f,0.f};

  const int ntile = (q0 + 15)/32 + 1;
  for (int kt = 0; kt < ntile; kt++){
    const int kbase = kt*32;
    const unsigned short* kp = K + (size_t)(kbase + lr)*HD + lq*8;
    floatx4 S0 = (floatx4){0.f,0.f,0.f,0.f};
    floatx4 S1 = (floatx4){0.f,0.f,0.f,0.f};
    S0 = MFMA16(qf0, *(const short8*)kp,             S0);
    S0 = MFMA16(qf1, *(const short8*)(kp + 32),      S0);
    S1 = MFMA16(qf0, *(const short8*)(kp + 16*HD),   S1);
    S1 = MFMA16(qf1, *(const short8*)(kp + 16*HD+32),S1);

    float p0[4], p1[4], mx[4], rs[4], al[4];
    const int qr = q0 + lq*4;
    #pragma unroll
    for (int r=0; r<4; r++){
      float s0 = S0[r]*0.125f; if (kbase + lr      > qr + r) s0 = -1e30f;
      float s1 = S1[r]*0.125f; if (kbase + 16 + lr > qr + r) s1 = -1e30f;
      p0[r] = s0; p1[r] = s1;
      mx[r] = fmaxf(s0, s1);
    }
    #pragma unroll
    for (int mm=1; mm<16; mm<<=1){
      #pragma unroll
      for (int r=0; r<4; r++) mx[r] = fmaxf(mx[r], __shfl_xor(mx[r], mm));
    }
    #pragma unroll
    for (int r=0; r<4; r++){
      const float mn = fmaxf(m[r], mx[r]);
      al[r] = __expf(m[r] - mn);
      m[r]  = mn;
      p0[r] = __expf(p0[r] - mn);
      p1[r] = __expf(p1[r] - mn);
      rs[r] = p0[r] + p1[r];
    }
    #pragma unroll
    for (int mm=1; mm<16; mm<<=1){
      #pragma unroll
      for (int r=0; r<4; r++) rs[r] += __shfl_xor(rs[r], mm);
    }
    floatx4 alv = (floatx4){al[0], al[1], al[2], al[3]};
    #pragma unroll
    for (int r=0; r<4; r++) lsum[r] = lsum[r]*al[r] + rs[r];
    #pragma unroll
    for (int nt=0; nt<4; nt++) O[nt] = O[nt]*alv;

    // P: C-layout -> A-layout through per-wave LDS slab (double buffered)
    unsigned short* pl = &plds[kt & 1][w][0];
    #pragma unroll
    for (int r=0; r<4; r++){
      const int row = lq*4 + r;
      pl[row*40 + lr]      = f2bf(p0[r]);
      pl[row*40 + 16 + lr] = f2bf(p1[r]);
    }
    __asm__ volatile("s_waitcnt lgkmcnt(0)" ::: "memory");
    const short8 pf = *(const short8*)(pl + lr*40 + lq*8);

    #pragma unroll
    for (int nt=0; nt<4; nt++){
      short8 vf = *(const short8*)(V + (size_t)(nt*16 + lr)*T_SEQ + kbase + lq*8);
      O[nt] = MFMA16(pf, vf, O[nt]);
    }
  }

  #pragma unroll
  for (int nt=0; nt<4; nt++){
    #pragma unroll
    for (int r=0; r<4; r++){
      const float o = O[nt][r] / lsum[r];
      yb[(size_t)(q0 + lq*4 + r)*DIM + head*HD + nt*16 + lr] = f2bf(o);
    }
  }
}

// ---------------- output projection (fp32 output!) ---------------------------
__global__ __launch_bounds__(256) void proj_kernel(
    const unsigned short* __restrict__ yb,
    const unsigned short* __restrict__ wpb,
    float* __restrict__ out){
  const int w  = threadIdx.x >> 6;
  const int l  = threadIdx.x & 63;
  const int lr = l & 15, lq = l >> 4;
  const int rb = blockIdx.x, cb = blockIdx.y;
  const int row0 = rb*64 + w*16;

  floatx4 acc[4];
  #pragma unroll
  for (int nt=0; nt<4; nt++) acc[nt] = (floatx4){0.f,0.f,0.f,0.f};

  const unsigned short* arow = yb + (size_t)(row0 + lr)*DIM + lq*8;
  const unsigned short* b0   = wpb + (size_t)(cb*64 + lr)*DIM + lq*8;
  for (int k0 = 0; k0 < DIM; k0 += 32){
    short8 a = *(const short8*)(arow + k0);
    #pragma unroll
    for (int nt = 0; nt < 4; nt++){
      short8 b = *(const short8*)(b0 + (size_t)nt*16*DIM + k0);
      acc[nt] = MFMA16(a, b, acc[nt]);
    }
  }
  #pragma unroll
  for (int nt=0; nt<4; nt++){
    #pragma unroll
    for (int r=0; r<4; r++){
      out[(size_t)(row0 + lq*4 + r)*DIM + cb*64 + nt*16 + lr] = acc[nt][r];
    }
  }
}

extern "C" void kernel_launch(void* const* d_in, const int* in_sizes, int n_in,
                              void* d_out, int out_size, void* d_ws, size_t ws_size,
                              hipStream_t stream){
  const float* x   = (const float*)d_in[0];
  const float* vi  = (const float*)d_in[1];
  const float* Wq  = (const float*)d_in[2];
  const float* Wk  = (const float*)d_in[3];
  const float* Wv  = (const float*)d_in[4];
  const float* Wp  = (const float*)d_in[5];
  const float* lamb= (const float*)d_in[6];

  const size_t XN = (size_t)T_SEQ*DIM;   // 1572864
  const size_t WN = (size_t)DIM*DIM;     // 589824
  char* ws = (char*)d_ws;
  unsigned short* xb    = (unsigned short*)ws; ws += XN*2;
  unsigned short* wqkvb = (unsigned short*)ws; ws += 3*WN*2;
  unsigned short* wpb   = (unsigned short*)ws; ws += WN*2;
  unsigned short* qb    = (unsigned short*)ws; ws += XN*2;
  unsigned short* kb    = (unsigned short*)ws; ws += XN*2;
  unsigned short* vT    = (unsigned short*)ws; ws += XN*2;
  unsigned short* yb    = xb;  // alias: xb dead after qkv_kernel

  convert_kernel<<<1024, 256, 0, stream>>>(x, Wq, Wk, Wv, Wp, xb, wqkvb, wpb);
  qkv_kernel<<<dim3(32,36), 256, 0, stream>>>(xb, wqkvb, vi, lamb, qb, kb, vT);
  attn_kernel<<<dim3(32,12), 256, 0, stream>>>(qb, kb, vT, yb);
  proj_kernel<<<dim3(32,12), 256, 0, stream>>>(yb, wpb, (float*)d_out);
}

// Round 4
// 248.870 us; speedup vs baseline: 1.1912x; 1.1912x over previous
//
#include <hip/hip_runtime.h>

#define T_SEQ 2048
#define DIM   768
#define NH    12
#define HD    64

typedef __attribute__((ext_vector_type(8))) short short8;
typedef __attribute__((ext_vector_type(4))) float floatx4;
typedef __attribute__((ext_vector_type(4))) unsigned short ushort4v;

#define MFMA16(a,b,c) __builtin_amdgcn_mfma_f32_16x16x32_bf16((a),(b),(c),0,0,0)

static __device__ __forceinline__ unsigned short f2bf(float f){
  union { float f; unsigned u; } v; v.f = f;
  unsigned r = v.u + 0x7fffu + ((v.u >> 16) & 1u);
  return (unsigned short)(r >> 16);
}
static __device__ __forceinline__ float bf2f(unsigned short u){
  union { unsigned u; float f; } v; v.u = ((unsigned)u) << 16;
  return v.f;
}

// ---------------- fp32 -> bf16 conversion of x, Wq|Wk|Wv, Wp ----------------
__global__ void convert_kernel(const float* __restrict__ x,
                               const float* __restrict__ wq,
                               const float* __restrict__ wk,
                               const float* __restrict__ wv,
                               const float* __restrict__ wp,
                               unsigned short* __restrict__ xb,
                               unsigned short* __restrict__ wqkvb,
                               unsigned short* __restrict__ wpb){
  const int stride = gridDim.x * blockDim.x;
  const int i0 = blockIdx.x * blockDim.x + threadIdx.x;
  const int XN = T_SEQ * DIM;
  const int WN = DIM * DIM;
  for (int i = i0; i < XN; i += stride) xb[i] = f2bf(x[i]);
  for (int i = i0; i < WN; i += stride) {
    wqkvb[i]        = f2bf(wq[i]);
    wqkvb[WN + i]   = f2bf(wk[i]);
    wqkvb[2*WN + i] = f2bf(wv[i]);
    wpb[i]          = f2bf(wp[i]);
  }
}

// ---------------- QKV projection + lerp + rmsnorm + rope --------------------
// grid (32 row-blocks, 36 col-blocks): cb/12 = {q,k,v}, cb%12 = head
__global__ __launch_bounds__(256) void qkv_kernel(
    const unsigned short* __restrict__ xb,
    const unsigned short* __restrict__ wqkvb,
    const float* __restrict__ vi,
    const float* __restrict__ lambp,
    unsigned short* __restrict__ qb,   // [NH][T][HD]
    unsigned short* __restrict__ kb,   // [NH][T][HD]
    unsigned short* __restrict__ vT){  // [NH][HD][T]
  const int w  = threadIdx.x >> 6;
  const int l  = threadIdx.x & 63;
  const int lr = l & 15, lq = l >> 4;
  const int rb = blockIdx.x, cb = blockIdx.y;
  const int mat = cb / NH, head = cb % NH;
  const int row0 = rb*64 + w*16;

  floatx4 acc[4];
  #pragma unroll
  for (int nt=0; nt<4; nt++) acc[nt] = (floatx4){0.f,0.f,0.f,0.f};

  const unsigned short* arow = xb + (size_t)(row0 + lr)*DIM + lq*8;
  const unsigned short* b0   = wqkvb + (size_t)mat*DIM*DIM
                             + (size_t)(head*HD + lr)*DIM + lq*8;
  for (int k0 = 0; k0 < DIM; k0 += 32){
    short8 a = *(const short8*)(arow + k0);
    #pragma unroll
    for (int nt = 0; nt < 4; nt++){
      short8 b = *(const short8*)(b0 + (size_t)nt*16*DIM + k0);
      acc[nt] = MFMA16(a, b, acc[nt]);
    }
  }

  if (mat == 2){
    const float lamb = *lambp;
    const int tb = row0 + lq*4;
    #pragma unroll
    for (int nt=0; nt<4; nt++){
      const int d = nt*16 + lr;
      ushort4v pk;
      #pragma unroll
      for (int r=0; r<4; r++){
        float vv = (1.0f - lamb)*acc[nt][r]
                 + lamb * vi[(size_t)(tb + r)*DIM + head*HD + d];
        pk[r] = f2bf(vv);
      }
      *(ushort4v*)(vT + (size_t)(head*HD + d)*T_SEQ + tb) = pk;
    }
  } else {
    float ss[4];
    #pragma unroll
    for (int r=0; r<4; r++)
      ss[r] = acc[0][r]*acc[0][r] + acc[1][r]*acc[1][r]
            + acc[2][r]*acc[2][r] + acc[3][r]*acc[3][r];
    #pragma unroll
    for (int mm=1; mm<16; mm<<=1){
      #pragma unroll
      for (int r=0; r<4; r++) ss[r] += __shfl_xor(ss[r], mm);
    }
    float scl[4];
    #pragma unroll
    for (int r=0; r<4; r++)
      scl[r] = rsqrtf(ss[r]*(1.0f/64.0f) + 1.1920929e-7f);

    unsigned short* dst = (mat==0 ? qb : kb) + (size_t)head*T_SEQ*HD;
    #pragma unroll
    for (int nt=0; nt<2; nt++){
      const int i = nt*16 + lr;                 // rope pair index, 0..31
      const float inv = __expf(-(float)i * (9.210340371976184f/32.0f));
      #pragma unroll
      for (int r=0; r<4; r++){
        const int t = row0 + lq*4 + r;
        const float f = (float)t * inv;
        const float c = cosf(f), s = sinf(f);
        const float x1 = acc[nt][r]*scl[r], x2 = acc[nt+2][r]*scl[r];
        dst[(size_t)t*HD + i]      = f2bf(x1*c + x2*s);
        dst[(size_t)t*HD + i + 32] = f2bf(x2*c - x1*s);
      }
    }
  }
}

// ---------------- causal flash attention (MFMA, split-K across 4 waves) -----
// grid (128 q-tiles, 12 heads); block = 4 waves; ALL waves share one 16-row
// q-tile; wave w processes key-tiles kt = w, w+4, w+8, ... (private online
// softmax state), then the 4 partials are merged through LDS.
__global__ __launch_bounds__(256) void attn_kernel(
    const unsigned short* __restrict__ qb,
    const unsigned short* __restrict__ kb,
    const unsigned short* __restrict__ vT,
    unsigned short* __restrict__ yb){   // [T][DIM] token-major
  __shared__ unsigned short plds[2][4][16*40];   // P transpose slab, 10240 B
  __shared__ unsigned short Osh[4][64][16];      // partial O (bf16), 8192 B
  __shared__ float msh[4][16], lsh[4][16];       // partial m/l, 512 B
  const int w  = threadIdx.x >> 6;
  const int l  = threadIdx.x & 63;
  const int lr = l & 15, lq = l >> 4;
  const int head = blockIdx.y;
  const int q0 = blockIdx.x*16;

  const unsigned short* Q = qb + (size_t)head*T_SEQ*HD;
  const unsigned short* K = kb + (size_t)head*T_SEQ*HD;
  const unsigned short* V = vT + (size_t)head*HD*T_SEQ;

  const short8 qf0 = *(const short8*)(Q + (size_t)(q0+lr)*HD + lq*8);
  const short8 qf1 = *(const short8*)(Q + (size_t)(q0+lr)*HD + 32 + lq*8);

  floatx4 O[4];
  #pragma unroll
  for (int nt=0; nt<4; nt++) O[nt] = (floatx4){0.f,0.f,0.f,0.f};
  float m[4]    = {-1e30f,-1e30f,-1e30f,-1e30f};
  float lsum[4] = {0.f,0.f,0.f,0.f};

  const int ntile = (q0 + 15)/32 + 1;   // 32-key tiles covering [0, q0+16)
  int dbuf = 0;
  for (int kt = w; kt < ntile; kt += 4, dbuf ^= 1){
    const int kbase = kt*32;
    const unsigned short* kp = K + (size_t)(kbase + lr)*HD + lq*8;
    floatx4 S0 = (floatx4){0.f,0.f,0.f,0.f};
    floatx4 S1 = (floatx4){0.f,0.f,0.f,0.f};
    S0 = MFMA16(qf0, *(const short8*)kp,             S0);
    S0 = MFMA16(qf1, *(const short8*)(kp + 32),      S0);
    S1 = MFMA16(qf0, *(const short8*)(kp + 16*HD),   S1);
    S1 = MFMA16(qf1, *(const short8*)(kp + 16*HD+32),S1);

    float p0[4], p1[4], mx[4], rs[4], al[4];
    const int qr = q0 + lq*4;
    #pragma unroll
    for (int r=0; r<4; r++){
      float s0 = S0[r]*0.125f; if (kbase + lr      > qr + r) s0 = -1e30f;
      float s1 = S1[r]*0.125f; if (kbase + 16 + lr > qr + r) s1 = -1e30f;
      p0[r] = s0; p1[r] = s1;
      mx[r] = fmaxf(s0, s1);
    }
    #pragma unroll
    for (int mm=1; mm<16; mm<<=1){
      #pragma unroll
      for (int r=0; r<4; r++) mx[r] = fmaxf(mx[r], __shfl_xor(mx[r], mm));
    }
    #pragma unroll
    for (int r=0; r<4; r++){
      const float mn = fmaxf(m[r], mx[r]);
      al[r] = __expf(m[r] - mn);
      m[r]  = mn;
      p0[r] = __expf(p0[r] - mn);
      p1[r] = __expf(p1[r] - mn);
      rs[r] = p0[r] + p1[r];
    }
    #pragma unroll
    for (int mm=1; mm<16; mm<<=1){
      #pragma unroll
      for (int r=0; r<4; r++) rs[r] += __shfl_xor(rs[r], mm);
    }
    floatx4 alv = (floatx4){al[0], al[1], al[2], al[3]};
    #pragma unroll
    for (int r=0; r<4; r++) lsum[r] = lsum[r]*al[r] + rs[r];
    #pragma unroll
    for (int nt=0; nt<4; nt++) O[nt] = O[nt]*alv;

    // P: C-layout -> A-layout through per-wave LDS slab (double buffered)
    unsigned short* pl = &plds[dbuf][w][0];
    #pragma unroll
    for (int r=0; r<4; r++){
      const int row = lq*4 + r;
      pl[row*40 + lr]      = f2bf(p0[r]);
      pl[row*40 + 16 + lr] = f2bf(p1[r]);
    }
    __asm__ volatile("s_waitcnt lgkmcnt(0)" ::: "memory");
    const short8 pf = *(const short8*)(pl + lr*40 + lq*8);

    #pragma unroll
    for (int nt=0; nt<4; nt++){
      short8 vf = *(const short8*)(V + (size_t)(nt*16 + lr)*T_SEQ + kbase + lq*8);
      O[nt] = MFMA16(pf, vf, O[nt]);
    }
  }

  // ---- publish partials ----
  if (lr == 0){
    #pragma unroll
    for (int r=0; r<4; r++){ msh[w][lq*4+r] = m[r]; lsh[w][lq*4+r] = lsum[r]; }
  }
  #pragma unroll
  for (int nt=0; nt<4; nt++){
    ushort4v pk;
    #pragma unroll
    for (int r=0; r<4; r++) pk[r] = f2bf(O[nt][r]);
    *(ushort4v*)&Osh[w][l][nt*4] = pk;
  }
  __syncthreads();

  // ---- wave 0 merges the 4 partials and writes out ----
  if (w == 0){
    float M[4], L[4] = {0.f,0.f,0.f,0.f};
    float Of[4][4];
    #pragma unroll
    for (int nt=0; nt<4; nt++)
      #pragma unroll
      for (int r=0; r<4; r++) Of[nt][r] = 0.f;
    #pragma unroll
    for (int r=0; r<4; r++){
      float mm_ = msh[0][lq*4+r];
      #pragma unroll
      for (int ww=1; ww<4; ww++) mm_ = fmaxf(mm_, msh[ww][lq*4+r]);
      M[r] = mm_;
    }
    #pragma unroll
    for (int ww=0; ww<4; ww++){
      float sc[4];
      #pragma unroll
      for (int r=0; r<4; r++){
        sc[r] = __expf(msh[ww][lq*4+r] - M[r]);
        L[r] += lsh[ww][lq*4+r]*sc[r];
      }
      #pragma unroll
      for (int nt=0; nt<4; nt++){
        ushort4v pk = *(const ushort4v*)&Osh[ww][l][nt*4];
        #pragma unroll
        for (int r=0; r<4; r++) Of[nt][r] += bf2f(pk[r])*sc[r];
      }
    }
    #pragma unroll
    for (int nt=0; nt<4; nt++){
      #pragma unroll
      for (int r=0; r<4; r++){
        yb[(size_t)(q0 + lq*4 + r)*DIM + head*HD + nt*16 + lr]
            = f2bf(Of[nt][r] / L[r]);
      }
    }
  }
}

// ---------------- output projection (fp32 output) ----------------------------
__global__ __launch_bounds__(256) void proj_kernel(
    const unsigned short* __restrict__ yb,
    const unsigned short* __restrict__ wpb,
    float* __restrict__ out){
  const int w  = threadIdx.x >> 6;
  const int l  = threadIdx.x & 63;
  const int lr = l & 15, lq = l >> 4;
  const int rb = blockIdx.x, cb = blockIdx.y;
  const int row0 = rb*64 + w*16;

  floatx4 acc[4];
  #pragma unroll
  for (int nt=0; nt<4; nt++) acc[nt] = (floatx4){0.f,0.f,0.f,0.f};

  const unsigned short* arow = yb + (size_t)(row0 + lr)*DIM + lq*8;
  const unsigned short* b0   = wpb + (size_t)(cb*64 + lr)*DIM + lq*8;
  for (int k0 = 0; k0 < DIM; k0 += 32){
    short8 a = *(const short8*)(arow + k0);
    #pragma unroll
    for (int nt = 0; nt < 4; nt++){
      short8 b = *(const short8*)(b0 + (size_t)nt*16*DIM + k0);
      acc[nt] = MFMA16(a, b, acc[nt]);
    }
  }
  #pragma unroll
  for (int nt=0; nt<4; nt++){
    #pragma unroll
    for (int r=0; r<4; r++){
      out[(size_t)(row0 + lq*4 + r)*DIM + cb*64 + nt*16 + lr] = acc[nt][r];
    }
  }
}

extern "C" void kernel_launch(void* const* d_in, const int* in_sizes, int n_in,
                              void* d_out, int out_size, void* d_ws, size_t ws_size,
                              hipStream_t stream){
  const float* x   = (const float*)d_in[0];
  const float* vi  = (const float*)d_in[1];
  const float* Wq  = (const float*)d_in[2];
  const float* Wk  = (const float*)d_in[3];
  const float* Wv  = (const float*)d_in[4];
  const float* Wp  = (const float*)d_in[5];
  const float* lamb= (const float*)d_in[6];

  const size_t XN = (size_t)T_SEQ*DIM;   // 1572864
  const size_t WN = (size_t)DIM*DIM;     // 589824
  char* ws = (char*)d_ws;
  unsigned short* xb    = (unsigned short*)ws; ws += XN*2;
  unsigned short* wqkvb = (unsigned short*)ws; ws += 3*WN*2;
  unsigned short* wpb   = (unsigned short*)ws; ws += WN*2;
  unsigned short* qb    = (unsigned short*)ws; ws += XN*2;
  unsigned short* kb    = (unsigned short*)ws; ws += XN*2;
  unsigned short* vT    = (unsigned short*)ws; ws += XN*2;
  unsigned short* yb    = xb;  // alias: xb dead after qkv_kernel

  convert_kernel<<<1024, 256, 0, stream>>>(x, Wq, Wk, Wv, Wp, xb, wqkvb, wpb);
  qkv_kernel<<<dim3(32,36), 256, 0, stream>>>(xb, wqkvb, vi, lamb, qb, kb, vT);
  attn_kernel<<<dim3(T_SEQ/16,12), 256, 0, stream>>>(qb, kb, vT, yb);
  proj_kernel<<<dim3(32,12), 256, 0, stream>>>(yb, wpb, (float*)d_out);
}

// Round 5
// 222.629 us; speedup vs baseline: 1.3316x; 1.1179x over previous
//
#include <hip/hip_runtime.h>

#define T_SEQ 2048
#define DIM   768
#define NH    12
#define HD    64

typedef __attribute__((ext_vector_type(8))) short short8;
typedef __attribute__((ext_vector_type(4))) float floatx4;
typedef __attribute__((ext_vector_type(4))) unsigned short ushort4v;

#define MFMA16(a,b,c) __builtin_amdgcn_mfma_f32_16x16x32_bf16((a),(b),(c),0,0,0)

static __device__ __forceinline__ unsigned short f2bf(float f){
  union { float f; unsigned u; } v; v.f = f;
  unsigned r = v.u + 0x7fffu + ((v.u >> 16) & 1u);
  return (unsigned short)(r >> 16);
}

// ---------------- fp32 -> bf16 conversion of x, Wq|Wk|Wv, Wp ----------------
__global__ void convert_kernel(const float* __restrict__ x,
                               const float* __restrict__ wq,
                               const float* __restrict__ wk,
                               const float* __restrict__ wv,
                               const float* __restrict__ wp,
                               unsigned short* __restrict__ xb,
                               unsigned short* __restrict__ wqkvb,
                               unsigned short* __restrict__ wpb){
  const int stride = gridDim.x * blockDim.x;
  const int i0 = blockIdx.x * blockDim.x + threadIdx.x;
  const int XN = T_SEQ * DIM;
  const int WN = DIM * DIM;
  for (int i = i0; i < XN; i += stride) xb[i] = f2bf(x[i]);
  for (int i = i0; i < WN; i += stride) {
    wqkvb[i]        = f2bf(wq[i]);
    wqkvb[WN + i]   = f2bf(wk[i]);
    wqkvb[2*WN + i] = f2bf(wv[i]);
    wpb[i]          = f2bf(wp[i]);
  }
}

// ---------------- QKV projection + lerp + rmsnorm + rope --------------------
__global__ __launch_bounds__(256) void qkv_kernel(
    const unsigned short* __restrict__ xb,
    const unsigned short* __restrict__ wqkvb,
    const float* __restrict__ vi,
    const float* __restrict__ lambp,
    unsigned short* __restrict__ qb,   // [NH][T][HD]
    unsigned short* __restrict__ kb,   // [NH][T][HD]
    unsigned short* __restrict__ vT){  // [NH][HD][T]
  const int w  = threadIdx.x >> 6;
  const int l  = threadIdx.x & 63;
  const int lr = l & 15, lq = l >> 4;
  const int rb = blockIdx.x, cb = blockIdx.y;
  const int mat = cb / NH, head = cb % NH;
  const int row0 = rb*64 + w*16;

  floatx4 acc[4];
  #pragma unroll
  for (int nt=0; nt<4; nt++) acc[nt] = (floatx4){0.f,0.f,0.f,0.f};

  const unsigned short* arow = xb + (size_t)(row0 + lr)*DIM + lq*8;
  const unsigned short* b0   = wqkvb + (size_t)mat*DIM*DIM
                             + (size_t)(head*HD + lr)*DIM + lq*8;
  for (int k0 = 0; k0 < DIM; k0 += 32){
    short8 a = *(const short8*)(arow + k0);
    #pragma unroll
    for (int nt = 0; nt < 4; nt++){
      short8 b = *(const short8*)(b0 + (size_t)nt*16*DIM + k0);
      acc[nt] = MFMA16(a, b, acc[nt]);
    }
  }

  if (mat == 2){
    const float lamb = *lambp;
    const int tb = row0 + lq*4;
    #pragma unroll
    for (int nt=0; nt<4; nt++){
      const int d = nt*16 + lr;
      ushort4v pk;
      #pragma unroll
      for (int r=0; r<4; r++){
        float vv = (1.0f - lamb)*acc[nt][r]
                 + lamb * vi[(size_t)(tb + r)*DIM + head*HD + d];
        pk[r] = f2bf(vv);
      }
      *(ushort4v*)(vT + (size_t)(head*HD + d)*T_SEQ + tb) = pk;
    }
  } else {
    float ss[4];
    #pragma unroll
    for (int r=0; r<4; r++)
      ss[r] = acc[0][r]*acc[0][r] + acc[1][r]*acc[1][r]
            + acc[2][r]*acc[2][r] + acc[3][r]*acc[3][r];
    #pragma unroll
    for (int mm=1; mm<16; mm<<=1){
      #pragma unroll
      for (int r=0; r<4; r++) ss[r] += __shfl_xor(ss[r], mm);
    }
    float scl[4];
    #pragma unroll
    for (int r=0; r<4; r++)
      scl[r] = rsqrtf(ss[r]*(1.0f/64.0f) + 1.1920929e-7f);

    unsigned short* dst = (mat==0 ? qb : kb) + (size_t)head*T_SEQ*HD;
    #pragma unroll
    for (int nt=0; nt<2; nt++){
      const int i = nt*16 + lr;                 // rope pair index, 0..31
      const float inv = __expf(-(float)i * (9.210340371976184f/32.0f));
      #pragma unroll
      for (int r=0; r<4; r++){
        const int t = row0 + lq*4 + r;
        const float f = (float)t * inv;
        const float c = cosf(f), s = sinf(f);
        const float x1 = acc[nt][r]*scl[r], x2 = acc[nt+2][r]*scl[r];
        dst[(size_t)t*HD + i]      = f2bf(x1*c + x2*s);
        dst[(size_t)t*HD + i + 32] = f2bf(x2*c - x1*s);
      }
    }
  }
}

// ---------------- causal flash attention (MFMA, fixed-max softmax) ----------
// Scores are bounded: rmsnorm rows have norm 8, so s = q.k/8 in [-8,8].
// Fixed max M=8 => no online max, no in-loop cross-lane reductions.
// grid (64, 12): block b handles q-tiles b and 127-b (balanced work).
// 4 waves split the key range of each q-tile (kt = w, w+4, ...), partial
// (O, l) summed through LDS (no rescale needed: all partials share M=8).
__global__ __launch_bounds__(256) void attn_kernel(
    const unsigned short* __restrict__ qb,
    const unsigned short* __restrict__ kb,
    const unsigned short* __restrict__ vT,
    unsigned short* __restrict__ yb){   // [T][DIM] token-major
  __shared__ unsigned short plds[2][4][16*40];   // P transpose slab, 10240 B
  __shared__ float Oshf[4][64][16];              // partial O fp32, 16384 B
  __shared__ float lsh[4][16];                   // partial l, 256 B
  const int w  = threadIdx.x >> 6;
  const int l  = threadIdx.x & 63;
  const int lr = l & 15, lq = l >> 4;
  const int head = blockIdx.y;

  const unsigned short* Q = qb + (size_t)head*T_SEQ*HD;
  const unsigned short* K = kb + (size_t)head*T_SEQ*HD;
  const unsigned short* V = vT + (size_t)head*HD*T_SEQ;

  #pragma unroll
  for (int ph = 0; ph < 2; ph++){
    const int qt = ph ? (127 - (int)blockIdx.x) : (int)blockIdx.x;
    const int q0 = qt*16;

    const short8 qf0 = *(const short8*)(Q + (size_t)(q0+lr)*HD + lq*8);
    const short8 qf1 = *(const short8*)(Q + (size_t)(q0+lr)*HD + 32 + lq*8);

    floatx4 O[4];
    #pragma unroll
    for (int nt=0; nt<4; nt++) O[nt] = (floatx4){0.f,0.f,0.f,0.f};
    float lsum[4] = {0.f,0.f,0.f,0.f};

    const int ntile = (q0 + 15)/32 + 1;
    int kt = w;
    short8 kf0, kf1, kf2, kf3;
    if (kt < ntile){
      const unsigned short* kp = K + (size_t)(kt*32 + lr)*HD + lq*8;
      kf0 = *(const short8*)kp;            kf1 = *(const short8*)(kp + 32);
      kf2 = *(const short8*)(kp + 16*HD);  kf3 = *(const short8*)(kp + 16*HD + 32);
    }
    int dbuf = 0;
    for (; kt < ntile; kt += 4, dbuf ^= 1){
      const int kbase = kt*32;
      // V fragments early (independent of softmax chain)
      short8 vf[4];
      #pragma unroll
      for (int nt=0; nt<4; nt++)
        vf[nt] = *(const short8*)(V + (size_t)(nt*16 + lr)*T_SEQ + kbase + lq*8);

      floatx4 S0 = (floatx4){0.f,0.f,0.f,0.f};
      floatx4 S1 = (floatx4){0.f,0.f,0.f,0.f};
      S0 = MFMA16(qf0, kf0, S0);
      S0 = MFMA16(qf1, kf1, S0);
      S1 = MFMA16(qf0, kf2, S1);
      S1 = MFMA16(qf1, kf3, S1);

      // prefetch next tile's K fragments (overlaps exp+LDS chain)
      const int ktn = kt + 4;
      if (ktn < ntile){
        const unsigned short* kp = K + (size_t)(ktn*32 + lr)*HD + lq*8;
        kf0 = *(const short8*)kp;            kf1 = *(const short8*)(kp + 32);
        kf2 = *(const short8*)(kp + 16*HD);  kf3 = *(const short8*)(kp + 16*HD + 32);
      }

      // p = exp2((s*0.125 - 8) * log2e), masked to 0 beyond diagonal
      float p0[4], p1[4];
      const int qr = q0 + lq*4;
      #pragma unroll
      for (int r=0; r<4; r++){
        float e0 = __builtin_amdgcn_exp2f(S0[r]*0.18033688011112043f - 11.541560327111707f);
        float e1 = __builtin_amdgcn_exp2f(S1[r]*0.18033688011112043f - 11.541560327111707f);
        p0[r] = (kbase + lr      > qr + r) ? 0.f : e0;
        p1[r] = (kbase + 16 + lr > qr + r) ? 0.f : e1;
        lsum[r] += p0[r] + p1[r];
      }

      // P: C-layout -> A-layout through per-wave LDS slab
      unsigned short* pl = &plds[dbuf][w][0];
      #pragma unroll
      for (int r=0; r<4; r++){
        const int row = lq*4 + r;
        pl[row*40 + lr]      = f2bf(p0[r]);
        pl[row*40 + 16 + lr] = f2bf(p1[r]);
      }
      __asm__ volatile("s_waitcnt lgkmcnt(0)" ::: "memory");
      const short8 pf = *(const short8*)(pl + lr*40 + lq*8);

      #pragma unroll
      for (int nt=0; nt<4; nt++) O[nt] = MFMA16(pf, vf[nt], O[nt]);
    }

    // one l-reduction per phase (lanes of a row group share rows lq*4+r)
    #pragma unroll
    for (int mm=1; mm<16; mm<<=1){
      #pragma unroll
      for (int r=0; r<4; r++) lsum[r] += __shfl_xor(lsum[r], mm);
    }

    // publish partials
    if (lr == 0){
      #pragma unroll
      for (int r=0; r<4; r++) lsh[w][lq*4+r] = lsum[r];
    }
    #pragma unroll
    for (int nt=0; nt<4; nt++) *(floatx4*)&Oshf[w][l][nt*4] = O[nt];
    __syncthreads();

    if (w == 0){
      float L[4] = {0.f,0.f,0.f,0.f};
      float Of[4][4];
      #pragma unroll
      for (int nt=0; nt<4; nt++)
        #pragma unroll
        for (int r=0; r<4; r++) Of[nt][r] = 0.f;
      #pragma unroll
      for (int ww=0; ww<4; ww++){
        #pragma unroll
        for (int r=0; r<4; r++) L[r] += lsh[ww][lq*4+r];
        #pragma unroll
        for (int nt=0; nt<4; nt++){
          floatx4 t = *(const floatx4*)&Oshf[ww][l][nt*4];
          #pragma unroll
          for (int r=0; r<4; r++) Of[nt][r] += t[r];
        }
      }
      #pragma unroll
      for (int nt=0; nt<4; nt++){
        #pragma unroll
        for (int r=0; r<4; r++){
          yb[(size_t)(q0 + lq*4 + r)*DIM + head*HD + nt*16 + lr]
              = f2bf(Of[nt][r] / L[r]);
        }
      }
    }
    __syncthreads();   // protect Oshf/lsh before next phase's publish
  }
}

// ---------------- output projection (fp32 output) ----------------------------
__global__ __launch_bounds__(256) void proj_kernel(
    const unsigned short* __restrict__ yb,
    const unsigned short* __restrict__ wpb,
    float* __restrict__ out){
  const int w  = threadIdx.x >> 6;
  const int l  = threadIdx.x & 63;
  const int lr = l & 15, lq = l >> 4;
  const int rb = blockIdx.x, cb = blockIdx.y;
  const int row0 = rb*64 + w*16;

  floatx4 acc[4];
  #pragma unroll
  for (int nt=0; nt<4; nt++) acc[nt] = (floatx4){0.f,0.f,0.f,0.f};

  const unsigned short* arow = yb + (size_t)(row0 + lr)*DIM + lq*8;
  const unsigned short* b0   = wpb + (size_t)(cb*64 + lr)*DIM + lq*8;
  for (int k0 = 0; k0 < DIM; k0 += 32){
    short8 a = *(const short8*)(arow + k0);
    #pragma unroll
    for (int nt = 0; nt < 4; nt++){
      short8 b = *(const short8*)(b0 + (size_t)nt*16*DIM + k0);
      acc[nt] = MFMA16(a, b, acc[nt]);
    }
  }
  #pragma unroll
  for (int nt=0; nt<4; nt++){
    #pragma unroll
    for (int r=0; r<4; r++){
      out[(size_t)(row0 + lq*4 + r)*DIM + cb*64 + nt*16 + lr] = acc[nt][r];
    }
  }
}

extern "C" void kernel_launch(void* const* d_in, const int* in_sizes, int n_in,
                              void* d_out, int out_size, void* d_ws, size_t ws_size,
                              hipStream_t stream){
  const float* x   = (const float*)d_in[0];
  const float* vi  = (const float*)d_in[1];
  const float* Wq  = (const float*)d_in[2];
  const float* Wk  = (const float*)d_in[3];
  const float* Wv  = (const float*)d_in[4];
  const float* Wp  = (const float*)d_in[5];
  const float* lamb= (const float*)d_in[6];

  const size_t XN = (size_t)T_SEQ*DIM;   // 1572864
  const size_t WN = (size_t)DIM*DIM;     // 589824
  char* ws = (char*)d_ws;
  unsigned short* xb    = (unsigned short*)ws; ws += XN*2;
  unsigned short* wqkvb = (unsigned short*)ws; ws += 3*WN*2;
  unsigned short* wpb   = (unsigned short*)ws; ws += WN*2;
  unsigned short* qb    = (unsigned short*)ws; ws += XN*2;
  unsigned short* kb    = (unsigned short*)ws; ws += XN*2;
  unsigned short* vT    = (unsigned short*)ws; ws += XN*2;
  unsigned short* yb    = xb;  // alias: xb dead after qkv_kernel

  convert_kernel<<<1024, 256, 0, stream>>>(x, Wq, Wk, Wv, Wp, xb, wqkvb, wpb);
  qkv_kernel<<<dim3(32,36), 256, 0, stream>>>(xb, wqkvb, vi, lamb, qb, kb, vT);
  attn_kernel<<<dim3(64,12), 256, 0, stream>>>(qb, kb, vT, yb);
  proj_kernel<<<dim3(32,12), 256, 0, stream>>>(yb, wpb, (float*)d_out);
}